// Round 7
// baseline (142.598 us; speedup 1.0000x reference)
//
#include <hip/hip_runtime.h>

#define BB 64
#define TT 4096
#define CC 51
#define DD 64
#define LN_EPS 1e-5f

typedef __attribute__((ext_vector_type(8))) short short8;
typedef __attribute__((ext_vector_type(4))) float f32x4;

union FragU { int i[4]; short8 s; };

// DPP control codes (verified R3-R6)
#define DPP_QP_1032   0xB1
#define DPP_QP_2301   0x4E
#define DPP_ROW_HMIRR 0x141
#define DPP_ROW_MIRR  0x140

__device__ __forceinline__ float dpp_add(float v, int tag) {
  int t;
  switch (tag) {
    case 0: t = __builtin_amdgcn_update_dpp(0, __float_as_int(v), DPP_QP_1032,   0xF, 0xF, true); break;
    case 1: t = __builtin_amdgcn_update_dpp(0, __float_as_int(v), DPP_QP_2301,   0xF, 0xF, true); break;
    case 2: t = __builtin_amdgcn_update_dpp(0, __float_as_int(v), DPP_ROW_HMIRR, 0xF, 0xF, true); break;
    default: t = __builtin_amdgcn_update_dpp(0, __float_as_int(v), DPP_ROW_MIRR, 0xF, 0xF, true); break;
  }
  return v + __int_as_float(t);
}
__device__ __forceinline__ float allsum16(float v) {
  v = dpp_add(v, 0); v = dpp_add(v, 1); v = dpp_add(v, 2); v = dpp_add(v, 3);
  return v;
}
__device__ __forceinline__ float allsum64(float v) {
  v = allsum16(v);
  v += __shfl_xor(v, 16, 64);
  v += __shfl_xor(v, 32, 64);
  return v;
}

// fp32 -> packed (bf16 hi | bf16 lo) dword; k=2c gets hi (low short), 2c+1 lo
__device__ __forceinline__ int pack_hl(float x) {
  const unsigned u = __float_as_uint(x);
  const unsigned h = u >> 16;
  const float hf = __uint_as_float(u & 0xFFFF0000u);
  const unsigned l = __float_as_uint(x - hf) >> 16;
  return (int)(h | (l << 16));
}

// ---- single fused kernel: no LDS, no barriers, one launch ----
// 2048 blocks x 256 thr; wave = 32 rows (2 M-tiles); 128 waves per batch b.
__global__ __launch_bounds__(256, 4)
void ipmask_fused7(const float* __restrict__ x, const float* __restrict__ W,
                   const float* __restrict__ Wm, const float* __restrict__ gamma,
                   const float* __restrict__ beta, const int* __restrict__ tmask,
                   const int* __restrict__ smask, float* __restrict__ out) {
  const int t = threadIdx.x, L = t & 63;
  const int q = L >> 4, m16 = L & 15;
  const int gw = (blockIdx.x << 2) + (t >> 6);      // 8192 waves
  const int b  = gw >> 7;                           // 128 waves per b
  const int rowBase = (b << 12) + ((gw & 127) << 5);

  const int* smB = smask + b * CC;

  // ---- x loads upfront (row-burst): 32 dwords/lane, lines fetched once ----
  FragU au[2][4];   // [mt][ks] packed A frags
#pragma unroll
  for (int mt = 0; mt < 2; ++mt) {
    const float* xr = x + (size_t)(rowBase + mt * 16 + m16) * CC;
#pragma unroll
    for (int ks = 0; ks < 4; ++ks) {
#pragma unroll
      for (int j = 0; j < 4; ++j) {
        const int c = ks * 16 + q * 4 + j;
        float xv = 0.0f;
        if (c < CC) xv = xr[c];
        au[mt][ks].i[j] = pack_hl(xv);
      }
    }
  }
  const int tmv = tmask[rowBase + (L & 31)];        // coalesced 128 B

  // ---- per-wave bias + fully-masked const row (Wm is L1-hot: 13 KB) ----
  float bs = 0.0f, f = 0.0f;
#pragma unroll
  for (int c = 0; c < CC; ++c) {
    const float wmv = Wm[c * DD + L];
    const float sf = (float)smB[c];
    bs = fmaf(sf, wmv, bs);
    f += wmv;
  }
  float constL;
  {
    const float s1 = allsum64(f);
    const float s2 = allsum64(f * f);
    const float mu = s1 * (1.0f / 64.0f);
    const float vr = fmaf(-mu, mu, s2 * (1.0f / 64.0f));
    const float rs = rsqrtf(vr + LN_EPS);
    constL = (f - mu) * rs;   // gamma/beta applied at epilogue
  }

  // ---- acc init = bias (column n = nt*16+m16 -> lane nt*16+m16's bs) ----
  f32x4 acc[2][4];
#pragma unroll
  for (int nt = 0; nt < 4; ++nt) {
    const float bias_nt = __shfl(bs, nt * 16 + m16, 64);
#pragma unroll
    for (int mt = 0; mt < 2; ++mt) {
      acc[mt][nt][0] = bias_nt; acc[mt][nt][1] = bias_nt;
      acc[mt][nt][2] = bias_nt; acc[mt][nt][3] = bias_nt;
    }
  }

  // ---- MFMA main loop: B frags rebuilt per ks (W is L1-hot) ----
#pragma unroll
  for (int ks = 0; ks < 4; ++ks) {
    FragU bmu[4], bcu[4];
#pragma unroll
    for (int j = 0; j < 4; ++j) {
      const int c = ks * 16 + q * 4 + j;
      const int smv = (c < CC) ? smB[c] : 1;
#pragma unroll
      for (int nt = 0; nt < 4; ++nt) {
        const int n = nt * 16 + m16;
        float we = 0.0f;
        if (c < CC) we = W[c * DD + n];
        if (smv) we = 0.0f;
        const unsigned u = __float_as_uint(we);
        const unsigned h = u >> 16;
        const float hf = __uint_as_float(u & 0xFFFF0000u);
        const unsigned l = __float_as_uint(we - hf) >> 16;
        bmu[nt].i[j] = (int)(h | (h << 16));   // (wh,wh) pairs (xh,xl)
        bcu[nt].i[j] = (int)l;                 // (wl,0)  pairs (xh,--)
      }
    }
#pragma unroll
    for (int mt = 0; mt < 2; ++mt) {
#pragma unroll
      for (int nt = 0; nt < 4; ++nt) {
        acc[mt][nt] = __builtin_amdgcn_mfma_f32_16x16x32_bf16(au[mt][ks].s, bmu[nt].s, acc[mt][nt], 0, 0, 0);
        acc[mt][nt] = __builtin_amdgcn_mfma_f32_16x16x32_bf16(au[mt][ks].s, bcu[nt].s, acc[mt][nt], 0, 0, 0);
      }
    }
  }

  // ---- epilogue: LN per row (16-lane DPP), tmask select, NT stores ----
  float g_[4], b_[4], cons_[4];
#pragma unroll
  for (int nt = 0; nt < 4; ++nt) {
    const int n = nt * 16 + m16;
    g_[nt] = gamma[n];
    b_[nt] = beta[n];
    cons_[nt] = fmaf(__shfl(constL, n, 64), g_[nt], b_[nt]);
  }
#pragma unroll
  for (int mt = 0; mt < 2; ++mt) {
#pragma unroll
    for (int rg = 0; rg < 4; ++rg) {
      float su = 0.0f, sq = 0.0f;
#pragma unroll
      for (int nt = 0; nt < 4; ++nt) {
        const float v = acc[mt][nt][rg];
        su += v;
        sq = fmaf(v, v, sq);
      }
      su = allsum16(su);
      sq = allsum16(sq);
      const float mu = su * (1.0f / 64.0f);
      const float vr = fmaf(-mu, mu, sq * (1.0f / 64.0f));
      const float rs = rsqrtf(vr + LN_EPS);
      const int rloc = mt * 16 + q * 4 + rg;       // 0..31
      const int tm = __shfl(tmv, rloc, 64);
      const size_t obase = (size_t)(rowBase + rloc) * DD;
#pragma unroll
      for (int nt = 0; nt < 4; ++nt) {
        float val = fmaf((acc[mt][nt][rg] - mu) * rs, g_[nt], b_[nt]);
        if (tm) val = cons_[nt];
        __builtin_nontemporal_store(val, &out[obase + nt * 16 + m16]);
      }
    }
  }
}

extern "C" void kernel_launch(void* const* d_in, const int* in_sizes, int n_in,
                              void* d_out, int out_size, void* d_ws, size_t ws_size,
                              hipStream_t stream) {
  const float* x     = (const float*)d_in[0];
  const float* W     = (const float*)d_in[1];
  const float* Wm    = (const float*)d_in[2];
  const float* gamma = (const float*)d_in[3];
  const float* beta  = (const float*)d_in[4];
  const int*   tmask = (const int*)d_in[5];
  const int*   smask = (const int*)d_in[6];
  float* out = (float*)d_out;

  ipmask_fused7<<<dim3(2048), dim3(256), 0, stream>>>(
      x, W, Wm, gamma, beta, tmask, smask, out);
}